// Round 4
// baseline (97.590 us; speedup 1.0000x reference)
//
#include <hip/hip_runtime.h>
#include <hip/hip_fp8.h>

#define N 8192
#define D 200
#define NSTEP 7            // 7 * 32 = 224 K fed to MFMA (200 real + fp8-zero pad)
#define TB 64              // tile edge, ONE TILE PER WAVE
#define NT 128             // tile grid dim = N/TB
#define TPP 129            // tiles per row-pair: row q has 128-q, row 127-q has q+1
#define NTILE (64 * TPP)   // 8256 triangle tiles == waves
#define NBLK (NTILE / 4)   // 2064 blocks of 4 independent waves
#define FSTEP 512          // bytes per fragment-step block (64 lanes x 8B)
#define PSTRIDE (NSTEP * FSTEP)  // 3584 B per 16-row panel
#define NPANEL (N / 16)          // 512 panels
#define XBSZ ((size_t)NPANEL * PSTRIDE)  // 1.84 MB, L2-resident
#define NPART NTILE

typedef float f32x4 __attribute__((ext_vector_type(4)));

// ---- prep: cast to fp8 e4m3, store in MFMA-fragment-native order ----
// Fragment block (panel p, step s) is 512B: lane l of a consuming wave reads
// byte l*8, holding row (l&15) of the panel, K-bytes (l>>4)*8.. within the
// 32B K-slice. So byte k of row r lands at:
//   p*3584 + (k/32)*512 + ((k%32)/8)*128 + (r%16)*8 + (k%8)
__global__ __launch_bounds__(256) void prep_kernel(
    const float* __restrict__ x, const int* __restrict__ labels,
    unsigned char* __restrict__ xb, float* __restrict__ sq,
    int* __restrict__ lab) {
  int row = blockIdx.x * 4 + (threadIdx.x >> 6);   // one wave per row
  int lane = threadIdx.x & 63;
  const float* xr = x + (size_t)row * D;
  int k0 = lane * 4;
  float4 f = {0.f, 0.f, 0.f, 0.f};
  if (k0 < D) f = *(const float4*)(xr + k0);       // lane<50 fully in-bounds
  float s = 0.f;
  unsigned char q[4];
  float ff[4] = {f.x, f.y, f.z, f.w};
#pragma unroll
  for (int c = 0; c < 4; ++c) {
    float v = (k0 + c < D) ? ff[c] : 0.f;
    __hip_fp8_e4m3 h(v);                           // OCP e4m3 RNE
    q[c] = h.__x;
    float fb = (float)h;
    s += fb * fb;                                  // norm of the fp8-rounded row
  }
  if (k0 < NSTEP * 32) {                           // lanes 0..55 (50..55 write zeros)
    unsigned char* dst = xb + (size_t)(row >> 4) * PSTRIDE
                       + (k0 >> 5) * FSTEP          // step
                       + ((k0 & 31) >> 3) * 128     // quad chunk
                       + (row & 15) * 8             // row within panel
                       + (k0 & 7);                  // 0 or 4
    *(uchar4*)dst = *(uchar4*)q;
  }
#pragma unroll
  for (int m = 32; m; m >>= 1) s += __shfl_xor(s, m);
  if (lane == 0) {
    sq[row] = s;
    lab[row] = labels[row];
  }
}

// ---- gram: wave-independent 64x64 tiles, fragments straight from L2 via
// ---- coalesced 512B loads. 2-deep ping-pong pipeline: step s+1's loads are
// ---- issued BEFORE step s's MFMAs, so compiler emits counted vmcnt (not 0)
// ---- and L2 latency hides under MFMA issue. launch_bounds(256,4) pins
// ---- VGPR<=128 -> 4 waves/SIMD. No LDS, no barriers, no atomics.
__global__ __launch_bounds__(256, 4) void gram_kernel(
    const unsigned char* __restrict__ xb, const float* __restrict__ sq,
    const int* __restrict__ lab, double* __restrict__ partial) {
  const int t = threadIdx.x;
  const int wid = t >> 6, lane = t & 63;
  const int w = blockIdx.x * 4 + wid;              // global wave id == tile id
  const int q = w / TPP, idx = w - q * TPP;        // row-pair decode
  const int n1 = NT - q;
  const int I = (idx < n1) ? q : NT - 1 - q;
  const int J = (idx < n1) ? q + idx : (NT - 1 - q) + (idx - n1);
  const int col = lane & 15, quad = lane >> 4;

  // 8 panel base pointers: every K-loop load is base + 13-bit immediate
  const unsigned char* Ap[4];
  const unsigned char* Bp[4];
#pragma unroll
  for (int k = 0; k < 4; ++k) {
    Ap[k] = xb + (size_t)(4 * I + k) * PSTRIDE + lane * 8;
    Bp[k] = xb + (size_t)(4 * J + k) * PSTRIDE + lane * 8;
  }

  long Af[2][4], Bf[2][4];
#pragma unroll
  for (int k = 0; k < 4; ++k) {                    // prologue: step 0 loads
    Af[0][k] = *(const long*)(Ap[k]);
    Bf[0][k] = *(const long*)(Bp[k]);
  }

  f32x4 acc[4][4] = {};
#pragma unroll
  for (int s = 0; s < NSTEP; ++s) {
    const int cb = s & 1, nb = cb ^ 1;             // unroll-constant indices
    if (s + 1 < NSTEP) {
#pragma unroll
      for (int k = 0; k < 4; ++k) {                // next step's loads FIRST
        Af[nb][k] = *(const long*)(Ap[k] + (s + 1) * FSTEP);
        Bf[nb][k] = *(const long*)(Bp[k] + (s + 1) * FSTEP);
      }
    }
#pragma unroll
    for (int mi = 0; mi < 4; ++mi)
#pragma unroll
      for (int ni = 0; ni < 4; ++ni)
        acc[mi][ni] = __builtin_amdgcn_mfma_f32_16x16x32_fp8_fp8(
            Af[cb][mi], Bf[cb][ni], acc[mi][ni], 0, 0, 0);
  }

  // ---- epilogue: D[m = quad*4 + r][n = col] (verified layout) ----
  const int i0 = I * TB, j0 = J * TB;
  int labj[4];
  float sqj[4];
#pragma unroll
  for (int ni = 0; ni < 4; ++ni) {
    int j = j0 + ni * 16 + col;
    labj[ni] = lab[j];
    sqj[ni] = sq[j];
  }
  float rs = 0.f, tot;
  if (I != J) {
#pragma unroll
    for (int mi = 0; mi < 4; ++mi) {
      float4 sqi4 = *(const float4*)(sq + i0 + mi * 16 + quad * 4);
      int4 li4 = *(const int4*)(lab + i0 + mi * 16 + quad * 4);
      float sqi[4] = {sqi4.x, sqi4.y, sqi4.z, sqi4.w};
      int li[4] = {li4.x, li4.y, li4.z, li4.w};
#pragma unroll
      for (int r = 0; r < 4; ++r) {
#pragma unroll
        for (int ni = 0; ni < 4; ++ni) {
          float g = acc[mi][ni][r];
          float d2 = fmaxf(fmaf(-2.f, g, sqi[r] + sqj[ni]), 0.f);
          float dist = __builtin_amdgcn_sqrtf(d2);
          rs += (li[r] == labj[ni]) ? dist : -dist;
        }
      }
    }
    tot = 2.f * rs;                                // mirror tile not launched
  } else {
#pragma unroll
    for (int mi = 0; mi < 4; ++mi) {
      float4 sqi4 = *(const float4*)(sq + i0 + mi * 16 + quad * 4);
      int4 li4 = *(const int4*)(lab + i0 + mi * 16 + quad * 4);
      float sqi[4] = {sqi4.x, sqi4.y, sqi4.z, sqi4.w};
      int li[4] = {li4.x, li4.y, li4.z, li4.w};
#pragma unroll
      for (int r = 0; r < 4; ++r) {
        int i = i0 + mi * 16 + quad * 4 + r;
#pragma unroll
        for (int ni = 0; ni < 4; ++ni) {
          int j = j0 + ni * 16 + col;
          float g = acc[mi][ni][r];
          float d2 = fmaxf(fmaf(-2.f, g, sqi[r] + sqj[ni]), 0.f);
          float dist = __builtin_amdgcn_sqrtf(d2);
          float c = (li[r] == labj[ni]) ? dist : -dist;
          rs += (i == j) ? 0.f : c;
        }
      }
    }
    tot = rs;
  }

  // per-wave partial: no LDS, no barrier, no atomics
#pragma unroll
  for (int m = 32; m; m >>= 1) tot += __shfl_xor(tot, m);
  if (lane == 0) partial[w] = (double)tot;
}

// ---------------- final mean ----------------
__global__ __launch_bounds__(256) void reduce_kernel(
    const double* __restrict__ partial, float* __restrict__ out) {
  __shared__ double wsum[4];
  double s = 0.0;
  for (int i = threadIdx.x; i < NPART; i += 256) s += partial[i];
#pragma unroll
  for (int m = 32; m; m >>= 1) s += __shfl_xor(s, m);
  if ((threadIdx.x & 63) == 0) wsum[threadIdx.x >> 6] = s;
  __syncthreads();
  if (threadIdx.x == 0)
    out[0] = (float)((wsum[0] + wsum[1] + wsum[2] + wsum[3]) / (double)N);
}

extern "C" void kernel_launch(void* const* d_in, const int* in_sizes, int n_in,
                              void* d_out, int out_size, void* d_ws, size_t ws_size,
                              hipStream_t stream) {
  const float* x = (const float*)d_in[0];
  const int* labels = (const int*)d_in[1];
  char* ws = (char*)d_ws;
  unsigned char* xb = (unsigned char*)ws;                      // XBSZ = 1.84 MB
  float* sq = (float*)(ws + XBSZ);                             // N*4
  int* lab = (int*)(ws + XBSZ + (size_t)N * 4);                // N*4
  double* partial = (double*)(ws + XBSZ + (size_t)N * 8);      // NPART*8
  float* out = (float*)d_out;

  prep_kernel<<<N / 4, 256, 0, stream>>>(x, labels, xb, sq, lab);
  gram_kernel<<<NBLK, 256, 0, stream>>>(xb, sq, lab, partial);
  reduce_kernel<<<1, 256, 0, stream>>>(partial, out);
}

// Round 5
// 82.321 us; speedup vs baseline: 1.1855x; 1.1855x over previous
//
#include <hip/hip_runtime.h>
#include <hip/hip_fp8.h>

#define N 8192
#define D 200
#define KP 232             // fp8 row stride BYTES: 58 dwords, gcd(58,32)=2 -> <=4-way LDS aliasing
#define NSTEP 7            // 7 * 32 = 224 K fed to MFMA (200 real + fp8-zero pad)
#define TB 128             // tile edge, ONE TILE PER BLOCK (4 waves, 64x64 quadrant each)
#define NT 64              // tile grid dim = N/TB
#define TPP 65             // tiles per row-pair: row q has 64-q, row 63-q has q+1
#define NBLK (32 * TPP)    // 2080 triangle tiles == blocks
#define PANEL (TB * KP)    // 29696 B, contiguous in global AND in LDS
#define NCELL 256

typedef float f32x4 __attribute__((ext_vector_type(4)));
#define AS3 __attribute__((address_space(3)))
#define AS1 __attribute__((address_space(1)))

// ---- prep: cast to fp8 e4m3 (padded to KP), row norms from fp8-decoded ----
// Block 0 also zeroes the 256 reduction cells (workspace is poisoned each iter).
__global__ __launch_bounds__(256) void prep_kernel(
    const float* __restrict__ x, const int* __restrict__ labels,
    unsigned char* __restrict__ xb, float* __restrict__ sq,
    int* __restrict__ lab, double* __restrict__ cells) {
  if (blockIdx.x == 0) cells[threadIdx.x] = 0.0;   // NCELL == blockDim
  int row = blockIdx.x * 4 + (threadIdx.x >> 6);   // one wave per row
  int lane = threadIdx.x & 63;
  const float* xr = x + (size_t)row * D;
  unsigned char* xbr = xb + (size_t)row * KP;
  int k0 = lane * 4;
  float4 f = {0.f, 0.f, 0.f, 0.f};
  if (k0 < D) f = *(const float4*)(xr + k0);       // lane<50 fully in-bounds
  float s = 0.f;
  unsigned char q[4];
  float ff[4] = {f.x, f.y, f.z, f.w};
#pragma unroll
  for (int c = 0; c < 4; ++c) {
    float v = (k0 + c < D) ? ff[c] : 0.f;
    __hip_fp8_e4m3 h(v);                           // OCP e4m3 RNE
    q[c] = h.__x;
    float fb = (float)h;
    s += fb * fb;                                  // norm of the fp8-rounded row
  }
  if (k0 < KP) *(uchar4*)(xbr + k0) = *(uchar4*)q; // lanes 0..57 (56,57 write zeros)
#pragma unroll
  for (int m = 32; m; m >>= 1) s += __shfl_xor(s, m);
  if (lane == 0) {
    sq[row] = s;
    lab[row] = labels[row];
  }
}

// ---- gram: one 128x128 tile per block; global_load_lds staging (bypasses
// ---- vL1D, the round-2/4 ingest bottleneck); 132 B per MFMA arithmetic
// ---- intensity; 2 blocks/CU alternate stage/compute; setprio biases the
// ---- computing block; per-wave f64 cell atomics (no ticket, no chains).
__global__ __launch_bounds__(256, 2) void gram_kernel(
    const unsigned char* __restrict__ xb, const float* __restrict__ sq,
    const int* __restrict__ lab, double* __restrict__ cells) {
  __shared__ __align__(16) unsigned char sA[PANEL];
  __shared__ __align__(16) unsigned char sB[PANEL];

  const int t = threadIdx.x;
  const int b = (blockIdx.x & 7) * (NBLK / 8) + (blockIdx.x >> 3);  // XCD swizzle (2080%8==0)
  const int q = b / TPP, idx = b - q * TPP;        // row-pair decode
  const int n1 = NT - q;
  const int I = (idx < n1) ? q : NT - 1 - q;
  const int J = (idx < n1) ? q + idx : (NT - 1 - q) + (idx - n1);

  auto stage = [&](const unsigned char* g, unsigned char* sh) {
#pragma unroll
    for (int c = 0; c < 7; ++c) {
      int off = c * 4096 + t * 16;
      __builtin_amdgcn_global_load_lds((const AS1 void*)(g + off),
                                       (AS3 void*)(sh + off), 16, 0, 0);
    }
    if (t < 64) {
      int off = 28672 + t * 16;
      __builtin_amdgcn_global_load_lds((const AS1 void*)(g + off),
                                       (AS3 void*)(sh + off), 16, 0, 0);
    }
  };
  stage(xb + (size_t)I * PANEL, sA);
  stage(xb + (size_t)J * PANEL, sB);

  // ---- hoisted epilogue operands (ride the same vmcnt drain as staging) ----
  const int wid = t >> 6, lane = t & 63;
  const int col = lane & 15, quad = lane >> 4;
  const int waveM = (wid >> 1) * 64, waveN = (wid & 1) * 64;
  const int i0 = I * TB + waveM, j0 = J * TB + waveN;
  int labj[4];
  float sqj[4];
#pragma unroll
  for (int ni = 0; ni < 4; ++ni) {
    int j = j0 + ni * 16 + col;
    labj[ni] = lab[j];
    sqj[ni] = sq[j];
  }
  float4 sqi4[4];
  int4 li4[4];
#pragma unroll
  for (int mi = 0; mi < 4; ++mi) {
    sqi4[mi] = *(const float4*)(sq + i0 + mi * 16 + quad * 4);
    li4[mi] = *(const int4*)(lab + i0 + mi * 16 + quad * 4);
  }
  __syncthreads();                                 // drains staging vmcnt + barrier

  // ---- K-loop from LDS ----
  f32x4 acc[4][4] = {};
  __builtin_amdgcn_s_setprio(1);
#pragma unroll
  for (int step = 0; step < NSTEP; ++step) {
    long a[4], bf[4];
#pragma unroll
    for (int mi = 0; mi < 4; ++mi)
      a[mi] = *(const long*)(sA + (waveM + mi * 16 + col) * KP + step * 32 + quad * 8);
#pragma unroll
    for (int ni = 0; ni < 4; ++ni)
      bf[ni] = *(const long*)(sB + (waveN + ni * 16 + col) * KP + step * 32 + quad * 8);
#pragma unroll
    for (int mi = 0; mi < 4; ++mi)
#pragma unroll
      for (int ni = 0; ni < 4; ++ni)
        acc[mi][ni] = __builtin_amdgcn_mfma_f32_16x16x32_fp8_fp8(
            a[mi], bf[ni], acc[mi][ni], 0, 0, 0);
  }
  __builtin_amdgcn_s_setprio(0);

  // ---- epilogue: D[m = quad*4 + r][n = col] (verified layout) ----
  float rs = 0.f, tot;
  if (I != J) {
#pragma unroll
    for (int mi = 0; mi < 4; ++mi) {
      float sqi[4] = {sqi4[mi].x, sqi4[mi].y, sqi4[mi].z, sqi4[mi].w};
      int li[4] = {li4[mi].x, li4[mi].y, li4[mi].z, li4[mi].w};
#pragma unroll
      for (int r = 0; r < 4; ++r)
#pragma unroll
        for (int ni = 0; ni < 4; ++ni) {
          float g = acc[mi][ni][r];
          float d2 = fmaxf(fmaf(-2.f, g, sqi[r] + sqj[ni]), 0.f);
          float dist = __builtin_amdgcn_sqrtf(d2);
          rs += (li[r] == labj[ni]) ? dist : -dist;
        }
    }
    tot = 2.f * rs;                                // mirror tile not launched
  } else {
#pragma unroll
    for (int mi = 0; mi < 4; ++mi) {
      float sqi[4] = {sqi4[mi].x, sqi4[mi].y, sqi4[mi].z, sqi4[mi].w};
      int li[4] = {li4[mi].x, li4[mi].y, li4[mi].z, li4[mi].w};
#pragma unroll
      for (int r = 0; r < 4; ++r) {
        int i = i0 + mi * 16 + quad * 4 + r;
#pragma unroll
        for (int ni = 0; ni < 4; ++ni) {
          int j = j0 + ni * 16 + col;
          float g = acc[mi][ni][r];
          float d2 = fmaxf(fmaf(-2.f, g, sqi[r] + sqj[ni]), 0.f);
          float dist = __builtin_amdgcn_sqrtf(d2);
          float c = (li[r] == labj[ni]) ? dist : -dist;
          rs += (i == j) ? 0.f : c;
        }
      }
    }
    tot = rs;
  }

  // ---- per-wave f64 scatter atomic (256 cells, ~32 adds/cell: no contention) ----
#pragma unroll
  for (int m = 32; m; m >>= 1) tot += __shfl_xor(tot, m);
  if (lane == 0)
    atomicAdd(&cells[(b * 4 + wid) & (NCELL - 1)], (double)tot);
}

// ---------------- final mean (256 doubles only) ----------------
__global__ __launch_bounds__(256) void reduce_kernel(
    const double* __restrict__ cells, float* __restrict__ out) {
  __shared__ double wsum[4];
  double s = cells[threadIdx.x];
#pragma unroll
  for (int m = 32; m; m >>= 1) s += __shfl_xor(s, m);
  if ((threadIdx.x & 63) == 0) wsum[threadIdx.x >> 6] = s;
  __syncthreads();
  if (threadIdx.x == 0)
    out[0] = (float)((wsum[0] + wsum[1] + wsum[2] + wsum[3]) / (double)N);
}

extern "C" void kernel_launch(void* const* d_in, const int* in_sizes, int n_in,
                              void* d_out, int out_size, void* d_ws, size_t ws_size,
                              hipStream_t stream) {
  const float* x = (const float*)d_in[0];
  const int* labels = (const int*)d_in[1];
  char* ws = (char*)d_ws;
  unsigned char* xb = (unsigned char*)ws;                         // N*KP = 1.9 MB
  float* sq = (float*)(ws + (size_t)N * KP);                      // N*4
  int* lab = (int*)(ws + (size_t)N * KP + (size_t)N * 4);         // N*4
  double* cells = (double*)(ws + (size_t)N * KP + (size_t)N * 8); // 256*8
  float* out = (float*)d_out;

  prep_kernel<<<N / 4, 256, 0, stream>>>(x, labels, xb, sq, lab, cells);
  gram_kernel<<<NBLK, 256, 0, stream>>>(xb, sq, lab, cells);
  reduce_kernel<<<1, 256, 0, stream>>>(cells, out);
}